// Round 9
// baseline (797.870 us; speedup 1.0000x reference)
//
#include <hip/hip_runtime.h>
#include <math.h>

typedef __attribute__((ext_vector_type(8)))  short  short8;
typedef __attribute__((ext_vector_type(4)))  short  short4v;
typedef __attribute__((ext_vector_type(16))) float  f32x16;
typedef __attribute__((ext_vector_type(4)))  float  f32x4v;

#define DT_F    ((float)(1.0/96.0))
#define SQDT_F  (0.10206207261596575f)
#define DF_F    (0.99968754882437816f)
#define RFR_F   (0.03f)

// swizzled LDS index for activations stored as [c][k] bf16, c in [0,32)
#define SWZ(c,k) (((c)<<7) + ((k) ^ (((c)&15)<<3)))

static __device__ __forceinline__ short f2bf(float x) {
    return __builtin_bit_cast(short, (__bf16)x);
}
static __device__ __forceinline__ float bf2f(short h) {
    return (float)__builtin_bit_cast(__bf16, h);
}

// layer 1: [t,S] -> 128 rows; wave wvm owns rows 32*wvm..+32, 32 cols
__device__ __forceinline__ void layer1(const float* __restrict__ Win, const float* __restrict__ bin_,
        float t, const float* __restrict__ sScur, ushort* __restrict__ out, int wvm, int l)
{
    const int g = l >> 4, c15 = l & 15;
    const int r0 = (wvm << 5) + (g << 3);
    float a8[8], w1[8];
#pragma unroll
    for (int jj = 0; jj < 8; ++jj) {
        const int r = r0 + jj;
        a8[jj] = fmaf(Win[2*r], t, bin_[r]);
        w1[jj] = Win[2*r + 1];
    }
#pragma unroll
    for (int cc = 0; cc < 2; ++cc) {
        const int c = c15 + (cc << 4);
        const float S = sScur[c];
        short8 v;
#pragma unroll
        for (int jj = 0; jj < 8; ++jj) {
            float h = fmaf(w1[jj], S, a8[jj]);
            h = fmaxf(h, 0.01f * h);            // leaky relu
            v[jj] = f2bf(h);
        }
        *(short8*)&out[SWZ(c, r0)] = v;
    }
}

// hidden 128x128 layer, bf16 weights streamed from L2; 32x32x16 MFMA
// wave wvm owns rows 32*wvm..+32, all 32 cols; 2 acc chains (even/odd kc)
__device__ __forceinline__ void hidden32(const ushort* __restrict__ WFm, const float* __restrict__ bias,
        const ushort* __restrict__ bin, ushort* __restrict__ bout, int wvm, int l)
{
    const int c0 = l & 31;
    const int l5 = l >> 5;
    const int kr = l5 << 3;
    f32x16 ae = {0,0,0,0,0,0,0,0,0,0,0,0,0,0,0,0};
    f32x16 ao = ae;
    const short8* fb = (const short8*)(WFm + (wvm << 12));   // rb = wvm
#pragma unroll
    for (int kc = 0; kc < 8; kc += 2) {
        short8 aE = fb[kc * 64 + l];
        short8 aO = fb[(kc + 1) * 64 + l];
        const int k0e = (kc << 4) + kr;
        short8 bE = *(const short8*)&bin[SWZ(c0, k0e)];
        short8 bO = *(const short8*)&bin[SWZ(c0, k0e + 16)];
        ae = __builtin_amdgcn_mfma_f32_32x32x16_bf16(aE, bE, ae, 0, 0, 0);
        ao = __builtin_amdgcn_mfma_f32_32x32x16_bf16(aO, bO, ao, 0, 0, 0);
    }
    const f32x16 acc = ae + ao;
    // C/D: row = (reg&3) + 8*(reg>>2) + 4*l5, col = c0
#pragma unroll
    for (int q = 0; q < 4; ++q) {
        const int rloc = (q << 3) + (l5 << 2);
        const f32x4v bq = *(const f32x4v*)&bias[(wvm << 5) + rloc];
        short4v o;
#pragma unroll
        for (int ii = 0; ii < 4; ++ii) {
            float x = acc[(q << 2) + ii] + bq[ii];
            o[ii] = f2bf(fmaxf(x, 0.01f * x));
        }
        *(short4v*)&bout[SWZ(c0, (wvm << 5) + rloc)] = o;
    }
}

__global__ __launch_bounds__(512, 2)
void sim_kernel(const float* __restrict__ normals, const float* __restrict__ strikes,
                const float* __restrict__ levWin, const float* __restrict__ levbin,
                const float* __restrict__ levbh,  const float* __restrict__ levWout,
                const float* __restrict__ levbout,
                const float* __restrict__ hedWin, const float* __restrict__ hedbin,
                const float* __restrict__ hedbh,  const float* __restrict__ hedbout,
                const ushort* __restrict__ WF, double* __restrict__ accD)
{
    __shared__ ushort bufL[2][32 * 128];   // lev ping-pong (8 KB each)
    __shared__ ushort bufH[2][32 * 128];   // hed ping-pong
    __shared__ float  sS[2][32];
    __shared__ float  sHc[32];

    const int tid  = threadIdx.x;
    const int wv   = tid >> 6;
    const int half = wv >> 2;      // 0 = lev chain, 1 = hed chain
    const int wvm  = wv & 3;
    const int l    = tid & 63;
    const int g    = l >> 4;
    const int c15  = l & 15;
    const int bp0  = blockIdx.x * 32;

    if (tid < 32) sS[0][tid] = 1.0f;
    float hedg[2][4];
#pragma unroll
    for (int a = 0; a < 2; ++a)
#pragma unroll
        for (int b = 0; b < 4; ++b) hedg[a][b] = 0.f;
    float dfim1 = 1.0f;
    __syncthreads();

    for (int i = 1; i <= 96; ++i) {
        const int idx = (i - 1) / 12;
        const float t = (float)(i - 1) * DT_F;
        const float* sScur = sS[(i - 1) & 1];
        float* sSnxt = sS[i & 1];
        const ushort* WFi = WF + (size_t)idx * 106496;
        const ushort* Wm  = WFi + ((half * 3) << 14);
        const float* bh   = (half ? hedbh : levbh) + idx * 384;
        ushort* buf0 = half ? bufH[0] : bufL[0];
        ushort* buf1 = half ? bufH[1] : bufL[1];

        // ---- W1: layer1 (both chains); lev waves 0-1 prefetch normals
        layer1((half ? hedWin : levWin) + idx * 256,
               (half ? hedbin : levbin) + (idx << 7), t, sScur, buf0, wvm, l);
        float nrm = 0.f;
        if (half == 0 && wvm < 2) nrm = normals[(i - 1) * 16384 + bp0 + c15 + (wvm << 4)];
        __syncthreads();                                    // b1

        hidden32(Wm,         bh,       buf0, buf1, wvm, l);
        __syncthreads();                                    // b2
        hidden32(Wm + 16384, bh + 128, buf1, buf0, wvm, l);
        __syncthreads();                                    // b3
        hidden32(Wm + 32768, bh + 256, buf0, buf1, wvm, l);
        __syncthreads();                                    // b4

        // ---- W5: lev out+SDE (waves 0-1) | hed hed-out MFMA
        const float dfi = dfim1 * DF_F;
        f32x4v acc0, acc1;
        if (half == 0) {
            if (wvm < 2) {
                const float* Wo = levWout + (idx << 7);
                float wk[32];
#pragma unroll
                for (int kb = 0; kb < 8; ++kb)
                    *(f32x4v*)&wk[4 * kb] = *(const f32x4v*)&Wo[(g << 5) + (kb << 2)];
                const int c = c15 + (wvm << 4);
                float p = 0.f;
#pragma unroll
                for (int kb = 0; kb < 4; ++kb) {
                    short8 hv = *(const short8*)&bufL[1][SWZ(c, (g << 5) + (kb << 3))];
#pragma unroll
                    for (int j = 0; j < 8; ++j) p = fmaf(bf2f(hv[j]), wk[(kb << 3) + j], p);
                }
                p += __shfl_xor(p, 16);
                p += __shfl_xor(p, 32);
                p += levbout[idx];
                const float lv = (p > 20.f) ? p : __logf(1.f + __expf(p));   // softplus
                const float S = sScur[c];
                const float drift = S * RFR_F / (1.f + fabsf(S * RFR_F) * SQDT_F);
                const float dif   = S * lv    / (1.f + fabsf(S * lv)   * SQDT_F);
                const float dW = SQDT_F * nrm;
                const float Sn = S + drift * DT_F + dif * dW;
                if (g == 0) { sSnxt[c] = Sn; sHc[c] = dfim1 * (S * dif) * dW; }
            }
        } else {
            // hed-out 64x128 via 16x16x32 MFMA; wave wvm owns rows 16*wvm..+16, 2 col-tiles
            const short8* fo = (const short8*)(WFi + 98304 + (wvm << 11));
            const f32x4v bo4 = *(const f32x4v*)&hedbout[(idx << 6) + (wvm << 4) + (g << 2)];
            acc0 = bo4; acc1 = bo4;   // bias as C-init
            __builtin_amdgcn_s_setprio(1);
#pragma unroll
            for (int kcq = 0; kcq < 4; ++kcq) {
                short8 a = fo[kcq * 64 + l];
                const int k0 = (kcq << 5) + (g << 3);
                short8 b0 = *(const short8*)&bufH[1][SWZ(c15,      k0)];
                short8 b1 = *(const short8*)&bufH[1][SWZ(16 + c15, k0)];
                acc0 = __builtin_amdgcn_mfma_f32_16x16x32_bf16(a, b0, acc0, 0, 0, 0);
                acc1 = __builtin_amdgcn_mfma_f32_16x16x32_bf16(a, b1, acc1, 0, 0, 0);
            }
            __builtin_amdgcn_s_setprio(0);
        }
        __syncthreads();                                    // b5

        if (half == 1) {
            // hedging accumulation; C/D row = 16*wvm + 4g + ii, col = 16*ct + c15
            const float hc0 = sHc[c15], hc1 = sHc[16 + c15];
#pragma unroll
            for (int ii = 0; ii < 4; ++ii) {
                hedg[0][ii] = fmaf(hc0, acc0[ii], hedg[0][ii]);
                hedg[1][ii] = fmaf(hc1, acc1[ii], hedg[1][ii]);
            }
            if ((i % 12) == 0) {   // maturity
                const int m = i / 12 - 1;
                const int isel = m & 3;
                const bool active = ((m >> 2) == (g & 1));
                const int ks = (wvm << 1) + (g >> 1);
                float s_ = 0.f, q_ = 0.f;
                if (active) {
                    const float K = strikes[ks];
#pragma unroll
                    for (int ct = 0; ct < 2; ++ct) {
                        const float* hrow = hedg[ct];
                        const float hv = (isel == 0) ? hrow[0] : (isel == 1) ? hrow[1]
                                        : (isel == 2) ? hrow[2] : hrow[3];
                        const float Sn = sSnxt[(ct << 4) + c15];
                        const float sim = dfi * fmaxf(Sn - K, 0.f) - hv;
                        s_ += sim; q_ += sim * sim;
                    }
                }
#pragma unroll
                for (int off = 1; off < 16; off <<= 1) {
                    s_ += __shfl_xor(s_, off);
                    q_ += __shfl_xor(q_, off);
                }
                if (active && c15 == 0) {
                    const int rep = blockIdx.x & 31;
                    atomicAdd(&accD[rep * 128 + ks * 8 + m], (double)s_);
                    atomicAdd(&accD[rep * 128 + 64 + ks * 8 + m], (double)q_);
                }
            }
        }
        dfim1 = dfi;
    }
}

// prep: pack bf16 weights into MFMA fragment order + zero accumulators
// per idx (106496 ushorts): 6x [128x128] hidden (16384 each, 32x32x16 frags) then [64x128] hed-out (8192, 16x16x32 frags)
__global__ void prep_kernel(const float* __restrict__ levWh, const float* __restrict__ hedWh,
                            const float* __restrict__ hedWout,
                            ushort* __restrict__ WF, double* __restrict__ accD)
{
    const long long stride = (long long)gridDim.x * blockDim.x;
    const long long t0 = (long long)blockIdx.x * blockDim.x + threadIdx.x;
    for (long long e = t0; e < 851968LL; e += stride) {
        const int idx = (int)(e / 106496);
        const int rem = (int)(e % 106496);
        float val;
        if (rem < 98304) {                        // 6 hidden matrices
            const int m    = rem >> 14;
            const int r2   = rem & 16383;
            const int slot = r2 >> 9;             // rb*8 + kc
            const int rb   = slot >> 3;
            const int kc   = slot & 7;
            const int lane = (r2 >> 3) & 63;
            const int j    = r2 & 7;
            const int r = (rb << 5) + (lane & 31);
            const int k = (kc << 4) + ((lane >> 5) << 3) + j;
            const float* src = (m < 3) ? levWh : hedWh;
            const int mm = (m < 3) ? m : m - 3;
            val = src[(((idx * 3 + mm) << 7) + r) * 128 + k];
        } else {                                  // hed-out 64x128
            const int r3   = rem - 98304;
            const int slot = r3 >> 9;             // rb*4 + kcq
            const int rb   = slot >> 2;
            const int kcq  = slot & 3;
            const int lane = (r3 >> 3) & 63;
            const int j    = r3 & 7;
            const int r = (rb << 4) + (lane & 15);
            const int k = (kcq << 5) + ((lane >> 4) << 3) + j;
            val = hedWout[(idx << 13) + (r << 7) + k];
        }
        WF[e] = (ushort)f2bf(val);
    }
    for (long long e = t0; e < 4096; e += stride) accD[e] = 0.0;
}

__global__ void finalize_kernel(const double* __restrict__ accD, float* __restrict__ out)
{
    const int t = threadIdx.x;
    if (t < 64) {
        double s = 0.0, q = 0.0;
        for (int rep = 0; rep < 32; ++rep) {
            s += accD[rep * 128 + t];
            q += accD[rep * 128 + 64 + t];
        }
        out[t]      = (float)(s / 16384.0);
        out[64 + t] = (float)((q - s * s / 16384.0) / 16383.0);
    }
}

extern "C" void kernel_launch(void* const* d_in, const int* in_sizes, int n_in,
                              void* d_out, int out_size, void* d_ws, size_t ws_size,
                              hipStream_t stream)
{
    const float* normals = (const float*)d_in[0];
    const float* strikes = (const float*)d_in[1];
    const float* levWin  = (const float*)d_in[2];
    const float* levbin  = (const float*)d_in[3];
    const float* levWh   = (const float*)d_in[4];
    const float* levbh   = (const float*)d_in[5];
    const float* levWout = (const float*)d_in[6];
    const float* levbout = (const float*)d_in[7];
    const float* hedWin  = (const float*)d_in[8];
    const float* hedbin  = (const float*)d_in[9];
    const float* hedWh   = (const float*)d_in[10];
    const float* hedbh   = (const float*)d_in[11];
    const float* hedWout = (const float*)d_in[12];
    const float* hedbout = (const float*)d_in[13];

    ushort* WF   = (ushort*)d_ws;                      // 851,968 ushorts = 1,703,936 B
    double* accD = (double*)((char*)d_ws + 1703936);   // 4096 doubles

    prep_kernel<<<1024, 256, 0, stream>>>(levWh, hedWh, hedWout, WF, accD);
    sim_kernel<<<512, 512, 0, stream>>>(normals, strikes,
                                        levWin, levbin, levbh, levWout, levbout,
                                        hedWin, hedbin, hedbh, hedbout,
                                        WF, accD);
    finalize_kernel<<<1, 64, 0, stream>>>(accD, (float*)d_out);
}

// Round 10
// 785.306 us; speedup vs baseline: 1.0160x; 1.0160x over previous
//
#include <hip/hip_runtime.h>
#include <math.h>

typedef __attribute__((ext_vector_type(8)))  short  short8;
typedef __attribute__((ext_vector_type(4)))  short  short4v;
typedef __attribute__((ext_vector_type(16))) float  f32x16;
typedef __attribute__((ext_vector_type(4)))  float  f32x4v;

#define DT_F    ((float)(1.0/96.0))
#define SQDT_F  (0.10206207261596575f)
#define DF_F    (0.99968754882437816f)
#define RFR_F   (0.03f)

// swizzled LDS index for activations stored as [c][k] bf16
#define SWZ(c,k) (((c)<<7) + ((k) ^ (((c)&15)<<3)))

static __device__ __forceinline__ short f2bf(float x) {
    return __builtin_bit_cast(short, (__bf16)x);
}
static __device__ __forceinline__ float bf2f(short h) {
    return (float)__builtin_bit_cast(__bf16, h);
}

// hidden 128x128 layer, one 32x32 output tile per wave (rows 32*rt, cols 32*ch),
// K=128, single acc chain, bias as MFMA C-init.
__device__ __forceinline__ void hidden_tile(const ushort* __restrict__ WFm,
        const float* __restrict__ bias,
        const ushort* __restrict__ bin, ushort* __restrict__ bout,
        int rt, int ch, int l, int l5)
{
    const int c0 = (l & 31) + (ch << 5);
    const int kr = l5 << 3;
    const float* bb = bias + (rt << 5);
    f32x16 acc;
#pragma unroll
    for (int q = 0; q < 4; ++q) {
        const f32x4v b4 = *(const f32x4v*)&bb[(q << 3) + (l5 << 2)];
#pragma unroll
        for (int ii = 0; ii < 4; ++ii) acc[(q << 2) + ii] = b4[ii];
    }
    const short8* fb = (const short8*)(WFm + (rt << 12));
#pragma unroll
    for (int kc = 0; kc < 8; ++kc) {
        short8 a = fb[kc * 64 + l];
        short8 b = *(const short8*)&bin[SWZ(c0, (kc << 4) + kr)];
        acc = __builtin_amdgcn_mfma_f32_32x32x16_bf16(a, b, acc, 0, 0, 0);
    }
    // C/D: row = (reg&3) + 8*(reg>>2) + 4*l5 (+32*rt), col = c0
#pragma unroll
    for (int q = 0; q < 4; ++q) {
        const int rloc = (rt << 5) + (q << 3) + (l5 << 2);
        short4v o;
#pragma unroll
        for (int ii = 0; ii < 4; ++ii) {
            float x = acc[(q << 2) + ii];
            o[ii] = f2bf(fmaxf(x, 0.01f * x));
        }
        *(short4v*)&bout[SWZ(c0, rloc)] = o;
    }
}

__global__ __launch_bounds__(1024, 4)
void sim_kernel(const float* __restrict__ normals, const float* __restrict__ strikes,
                const float* __restrict__ levWin, const float* __restrict__ levbin,
                const float* __restrict__ levbh,  const float* __restrict__ levWout,
                const float* __restrict__ levbout,
                const float* __restrict__ hedWin, const float* __restrict__ hedbin,
                const float* __restrict__ hedbh,  const float* __restrict__ hedbout,
                const ushort* __restrict__ WF, double* __restrict__ accD)
{
    __shared__ ushort bufL[2][64 * 128];   // lev ping-pong (16 KB each)
    __shared__ ushort bufH[2][64 * 128];   // hed ping-pong
    __shared__ float  sS[2][64];
    __shared__ float  sHc[64];

    const int tid   = threadIdx.x;
    const int wv    = tid >> 6;        // 0..15
    const int chain = wv >> 3;         // 0 = lev, 1 = hed
    const int w8    = wv & 7;          // wave within chain
    const int l     = tid & 63;
    const int g     = l >> 4;
    const int c15   = l & 15;
    const int l5    = l >> 5;
    const int rt    = w8 & 3;          // hidden row-tile (32 rows)
    const int ch    = w8 >> 2;         // hidden col-half (32 cols)
    const int bp0   = blockIdx.x * 64;

    if (tid < 64) sS[0][tid] = 1.0f;
    float hedg[2][4];
#pragma unroll
    for (int a = 0; a < 2; ++a)
#pragma unroll
        for (int b = 0; b < 4; ++b) hedg[a][b] = 0.f;
    float dfim1 = 1.0f;
    __syncthreads();

    for (int i = 1; i <= 96; ++i) {
        const int idx = (i - 1) / 12;
        const float t = (float)(i - 1) * DT_F;
        const float* sScur = sS[(i - 1) & 1];
        float* sSnxt = sS[i & 1];
        const ushort* WFi = WF + (size_t)idx * 106496;
        const ushort* Wm  = WFi + ((chain * 3) << 14);
        const float* bh   = (chain ? hedbh : levbh) + idx * 384;
        ushort* b0p = chain ? bufH[0] : bufL[0];
        ushort* b1p = chain ? bufH[1] : bufL[1];

        // ---- W1: layer1, rows 16*w8..+16, lane = col
        {
            const float* Win = (chain ? hedWin : levWin) + idx * 256;
            const float* bi  = (chain ? hedbin : levbin) + (idx << 7);
            const int r0 = w8 << 4;
            const float S = sScur[l];
            short8 v0, v1;
#pragma unroll
            for (int j = 0; j < 8; ++j) {
                const int r = r0 + j;
                float h = fmaf(Win[2*r], t, fmaf(Win[2*r+1], S, bi[r]));
                v0[j] = f2bf(fmaxf(h, 0.01f * h));
            }
#pragma unroll
            for (int j = 0; j < 8; ++j) {
                const int r = r0 + 8 + j;
                float h = fmaf(Win[2*r], t, fmaf(Win[2*r+1], S, bi[r]));
                v1[j] = f2bf(fmaxf(h, 0.01f * h));
            }
            *(short8*)&b0p[SWZ(l, r0)]     = v0;
            *(short8*)&b0p[SWZ(l, r0 + 8)] = v1;
        }
        __syncthreads();                                    // b1

        hidden_tile(Wm,         bh,       b0p, b1p, rt, ch, l, l5);
        __syncthreads();                                    // b2
        hidden_tile(Wm + 16384, bh + 128, b1p, b0p, rt, ch, l, l5);
        __syncthreads();                                    // b3
        hidden_tile(Wm + 32768, bh + 256, b0p, b1p, rt, ch, l, l5);
        __syncthreads();                                    // b4

        // ---- W5: lev: lev-out + SDE (8 cols/wave) | hed: hed-out MFMA (2 16x16 tiles/wave)
        const float dfi = dfim1 * DF_F;
        f32x4v acc0, acc1;
        if (chain == 0) {
            const int col = (w8 << 3) + (l >> 3);
            const int kk  = l & 7;
            const int k0  = kk << 4;
            const float nrm = normals[(size_t)(i - 1) * 16384 + bp0 + col];
            const float* Wo = levWout + (idx << 7);
            const f32x4v w0 = *(const f32x4v*)&Wo[k0];
            const f32x4v w1 = *(const f32x4v*)&Wo[k0 + 4];
            const f32x4v w2 = *(const f32x4v*)&Wo[k0 + 8];
            const f32x4v w3 = *(const f32x4v*)&Wo[k0 + 12];
            const short8 h0 = *(const short8*)&bufL[1][SWZ(col, k0)];
            const short8 h1 = *(const short8*)&bufL[1][SWZ(col, k0 + 8)];
            float p = 0.f;
#pragma unroll
            for (int j = 0; j < 4; ++j) p = fmaf(bf2f(h0[j]),     w0[j], p);
#pragma unroll
            for (int j = 0; j < 4; ++j) p = fmaf(bf2f(h0[4 + j]), w1[j], p);
#pragma unroll
            for (int j = 0; j < 4; ++j) p = fmaf(bf2f(h1[j]),     w2[j], p);
#pragma unroll
            for (int j = 0; j < 4; ++j) p = fmaf(bf2f(h1[4 + j]), w3[j], p);
            p += __shfl_xor(p, 1);
            p += __shfl_xor(p, 2);
            p += __shfl_xor(p, 4);
            p += levbout[idx];
            const float lv = (p > 20.f) ? p : __logf(1.f + __expf(p));   // softplus
            const float S = sScur[col];
            const float drift = S * RFR_F / (1.f + fabsf(S * RFR_F) * SQDT_F);
            const float dif   = S * lv    / (1.f + fabsf(S * lv)   * SQDT_F);
            const float dW = SQDT_F * nrm;
            const float Sn = S + drift * DT_F + dif * dW;
            if (kk == 0) { sSnxt[col] = Sn; sHc[col] = dfim1 * (S * dif) * dW; }
        } else {
            // rows 16*rt..+16, cols 32*ch + {0,16}
            const short8* fo = (const short8*)(WFi + 98304 + (rt << 11));
            const f32x4v bo4 = *(const f32x4v*)&hedbout[(idx << 6) + (rt << 4) + (g << 2)];
            acc0 = bo4; acc1 = bo4;   // bias as C-init
            __builtin_amdgcn_s_setprio(1);
#pragma unroll
            for (int kcq = 0; kcq < 4; ++kcq) {
                short8 a = fo[kcq * 64 + l];
                const int k0 = (kcq << 5) + (g << 3);
                short8 b0 = *(const short8*)&bufH[1][SWZ((ch << 5) + c15,      k0)];
                short8 b1 = *(const short8*)&bufH[1][SWZ((ch << 5) + 16 + c15, k0)];
                acc0 = __builtin_amdgcn_mfma_f32_16x16x32_bf16(a, b0, acc0, 0, 0, 0);
                acc1 = __builtin_amdgcn_mfma_f32_16x16x32_bf16(a, b1, acc1, 0, 0, 0);
            }
            __builtin_amdgcn_s_setprio(0);
        }
        __syncthreads();                                    // b5

        if (chain == 1) {
            // hedging accumulation; C/D row = 16*rt + 4g + ii, col = 32*ch + 16*t + c15
            const float hc0 = sHc[(ch << 5) + c15];
            const float hc1 = sHc[(ch << 5) + 16 + c15];
#pragma unroll
            for (int ii = 0; ii < 4; ++ii) {
                hedg[0][ii] = fmaf(hc0, acc0[ii], hedg[0][ii]);
                hedg[1][ii] = fmaf(hc1, acc1[ii], hedg[1][ii]);
            }
            if ((i % 12) == 0) {   // maturity
                const int m = i / 12 - 1;
                const int isel = m & 3;
                const bool active = ((g & 1) == (m >> 2));
                const int strike = (rt << 1) + (g >> 1);
                float s_ = 0.f, q_ = 0.f;
                if (active) {
                    const float K = strikes[strike];
#pragma unroll
                    for (int t2 = 0; t2 < 2; ++t2) {
                        const float* hrow = hedg[t2];
                        const float hv = (isel == 0) ? hrow[0] : (isel == 1) ? hrow[1]
                                        : (isel == 2) ? hrow[2] : hrow[3];
                        const float Sn = sSnxt[(ch << 5) + (t2 << 4) + c15];
                        const float sim = dfi * fmaxf(Sn - K, 0.f) - hv;
                        s_ += sim; q_ += sim * sim;
                    }
                }
#pragma unroll
                for (int off = 1; off < 16; off <<= 1) {
                    s_ += __shfl_xor(s_, off);
                    q_ += __shfl_xor(q_, off);
                }
                if (active && c15 == 0) {
                    const int rep = blockIdx.x & 31;
                    atomicAdd(&accD[rep * 128 + strike * 8 + m], (double)s_);
                    atomicAdd(&accD[rep * 128 + 64 + strike * 8 + m], (double)q_);
                }
            }
        }
        dfim1 = dfi;
    }
}

// prep: pack bf16 weights into MFMA fragment order + zero accumulators
// per idx (106496 ushorts): 6x [128x128] hidden (16384 each, 32x32x16 frags) then [64x128] hed-out (8192, 16x16x32 frags)
__global__ void prep_kernel(const float* __restrict__ levWh, const float* __restrict__ hedWh,
                            const float* __restrict__ hedWout,
                            ushort* __restrict__ WF, double* __restrict__ accD)
{
    const long long stride = (long long)gridDim.x * blockDim.x;
    const long long t0 = (long long)blockIdx.x * blockDim.x + threadIdx.x;
    for (long long e = t0; e < 851968LL; e += stride) {
        const int idx = (int)(e / 106496);
        const int rem = (int)(e % 106496);
        float val;
        if (rem < 98304) {                        // 6 hidden matrices
            const int m    = rem >> 14;
            const int r2   = rem & 16383;
            const int slot = r2 >> 9;             // rb*8 + kc
            const int rb   = slot >> 3;
            const int kc   = slot & 7;
            const int lane = (r2 >> 3) & 63;
            const int j    = r2 & 7;
            const int r = (rb << 5) + (lane & 31);
            const int k = (kc << 4) + ((lane >> 5) << 3) + j;
            const float* src = (m < 3) ? levWh : hedWh;
            const int mm = (m < 3) ? m : m - 3;
            val = src[(((idx * 3 + mm) << 7) + r) * 128 + k];
        } else {                                  // hed-out 64x128
            const int r3   = rem - 98304;
            const int slot = r3 >> 9;             // rb*4 + kcq
            const int rb   = slot >> 2;
            const int kcq  = slot & 3;
            const int lane = (r3 >> 3) & 63;
            const int j    = r3 & 7;
            const int r = (rb << 4) + (lane & 15);
            const int k = (kcq << 5) + ((lane >> 4) << 3) + j;
            val = hedWout[(idx << 13) + (r << 7) + k];
        }
        WF[e] = (ushort)f2bf(val);
    }
    for (long long e = t0; e < 4096; e += stride) accD[e] = 0.0;
}

__global__ void finalize_kernel(const double* __restrict__ accD, float* __restrict__ out)
{
    const int t = threadIdx.x;
    if (t < 64) {
        double s = 0.0, q = 0.0;
        for (int rep = 0; rep < 32; ++rep) {
            s += accD[rep * 128 + t];
            q += accD[rep * 128 + 64 + t];
        }
        out[t]      = (float)(s / 16384.0);
        out[64 + t] = (float)((q - s * s / 16384.0) / 16383.0);
    }
}

extern "C" void kernel_launch(void* const* d_in, const int* in_sizes, int n_in,
                              void* d_out, int out_size, void* d_ws, size_t ws_size,
                              hipStream_t stream)
{
    const float* normals = (const float*)d_in[0];
    const float* strikes = (const float*)d_in[1];
    const float* levWin  = (const float*)d_in[2];
    const float* levbin  = (const float*)d_in[3];
    const float* levWh   = (const float*)d_in[4];
    const float* levbh   = (const float*)d_in[5];
    const float* levWout = (const float*)d_in[6];
    const float* levbout = (const float*)d_in[7];
    const float* hedWin  = (const float*)d_in[8];
    const float* hedbin  = (const float*)d_in[9];
    const float* hedWh   = (const float*)d_in[10];
    const float* hedbh   = (const float*)d_in[11];
    const float* hedWout = (const float*)d_in[12];
    const float* hedbout = (const float*)d_in[13];

    ushort* WF   = (ushort*)d_ws;                      // 851,968 ushorts = 1,703,936 B
    double* accD = (double*)((char*)d_ws + 1703936);   // 4096 doubles

    prep_kernel<<<1024, 256, 0, stream>>>(levWh, hedWh, hedWout, WF, accD);
    sim_kernel<<<256, 1024, 0, stream>>>(normals, strikes,
                                         levWin, levbin, levbh, levWout, levbout,
                                         hedWin, hedbin, hedbh, hedbout,
                                         WF, accD);
    finalize_kernel<<<1, 64, 0, stream>>>(accD, (float*)d_out);
}

// Round 11
// 552.166 us; speedup vs baseline: 1.4450x; 1.4222x over previous
//
#include <hip/hip_runtime.h>
#include <math.h>

typedef __attribute__((ext_vector_type(8)))  short  short8;
typedef __attribute__((ext_vector_type(4)))  short  short4v;
typedef __attribute__((ext_vector_type(16))) float  f32x16;
typedef __attribute__((ext_vector_type(4)))  float  f32x4v;

#define DT_F    ((float)(1.0/96.0))
#define SQDT_F  (0.10206207261596575f)
#define DF_F    (0.99968754882437816f)
#define RFR_F   (0.03f)

// swizzled LDS index for activations stored as [c][k] bf16
// 16-slot XOR spread (R7/R10: bank conflicts 6.45e7 -> ~2e7 vs 8-slot)
#define SWZ(c,k) (((c)<<7) + ((k) ^ (((c)&15)<<3)))

static __device__ __forceinline__ short f2bf(float x) {
    return __builtin_bit_cast(short, (__bf16)x);
}
static __device__ __forceinline__ float bf2f(short h) {
    return (float)__builtin_bit_cast(__bf16, h);
}

// layer 1: [t,S] -> 128 rows; wave-of-MLP wvm owns rows 32*wvm..+32, all 64 cols
__device__ __forceinline__ void layer1(const float* __restrict__ Win, const float* __restrict__ bin_,
        float t, const float* __restrict__ sScur, ushort* __restrict__ out, int wvm, int l)
{
    const int g = l >> 4, c15 = l & 15;
    const int r0 = (wvm << 5) + (g << 3);
    float a8[8], w1[8];
#pragma unroll
    for (int jj = 0; jj < 8; ++jj) {
        const int r = r0 + jj;
        a8[jj] = fmaf(Win[2*r], t, bin_[r]);
        w1[jj] = Win[2*r + 1];
    }
#pragma unroll
    for (int cc = 0; cc < 4; ++cc) {
        const int c = c15 + (cc << 4);
        const float S = sScur[c];
        short8 v;
#pragma unroll
        for (int jj = 0; jj < 8; ++jj) {
            float h = fmaf(w1[jj], S, a8[jj]);
            h = fmaxf(h, 0.01f * h);            // leaky relu
            v[jj] = f2bf(h);
        }
        *(short8*)&out[SWZ(c, r0)] = v;
    }
}

// hidden 128x128 layer, bf16 weights streamed from L2; 32x32x16 MFMA; wvm owns rows 32*wvm..+32
// 4 independent accumulator chains (even/odd kc x 2 col-tiles)
__device__ __forceinline__ void hidden32(const ushort* __restrict__ WFm, const float* __restrict__ bias,
        const ushort* __restrict__ bin, ushort* __restrict__ bout, int wvm, int l)
{
    const int c0 = l & 31;
    const int l5 = l >> 5;
    const int kr = l5 << 3;
    f32x16 a0e = {0,0,0,0,0,0,0,0,0,0,0,0,0,0,0,0};
    f32x16 a0o = a0e, a1e = a0e, a1o = a0e;
    const short8* fb = (const short8*)(WFm + (wvm << 12));   // rb = wvm
#pragma unroll
    for (int kc = 0; kc < 8; kc += 2) {
        short8 aE = fb[kc * 64 + l];
        short8 aO = fb[(kc + 1) * 64 + l];
        const int k0e = (kc << 4) + kr;
        const int k0o = k0e + 16;
        short8 b0e = *(const short8*)&bin[SWZ(c0,      k0e)];
        short8 b1e = *(const short8*)&bin[SWZ(c0 + 32, k0e)];
        short8 b0o = *(const short8*)&bin[SWZ(c0,      k0o)];
        short8 b1o = *(const short8*)&bin[SWZ(c0 + 32, k0o)];
        a0e = __builtin_amdgcn_mfma_f32_32x32x16_bf16(aE, b0e, a0e, 0, 0, 0);
        a1e = __builtin_amdgcn_mfma_f32_32x32x16_bf16(aE, b1e, a1e, 0, 0, 0);
        a0o = __builtin_amdgcn_mfma_f32_32x32x16_bf16(aO, b0o, a0o, 0, 0, 0);
        a1o = __builtin_amdgcn_mfma_f32_32x32x16_bf16(aO, b1o, a1o, 0, 0, 0);
    }
    const f32x16 acc0 = a0e + a0o;
    const f32x16 acc1 = a1e + a1o;
    // C/D: row = (reg&3) + 8*(reg>>2) + 4*l5, col = c0
#pragma unroll
    for (int q = 0; q < 4; ++q) {
        const int rloc = (q << 3) + (l5 << 2);
        const f32x4v bq = *(const f32x4v*)&bias[(wvm << 5) + rloc];
        short4v o0, o1;
#pragma unroll
        for (int ii = 0; ii < 4; ++ii) {
            float x0 = acc0[(q << 2) + ii] + bq[ii]; o0[ii] = f2bf(fmaxf(x0, 0.01f * x0));
            float x1 = acc1[(q << 2) + ii] + bq[ii]; o1[ii] = f2bf(fmaxf(x1, 0.01f * x1));
        }
        *(short4v*)&bout[SWZ(c0,      (wvm << 5) + rloc)] = o0;
        *(short4v*)&bout[SWZ(c0 + 32, (wvm << 5) + rloc)] = o1;
    }
}

__global__ __launch_bounds__(512, 2)
void sim_kernel(const float* __restrict__ normals, const float* __restrict__ strikes,
                const float* __restrict__ levWin, const float* __restrict__ levbin,
                const float* __restrict__ levbh,  const float* __restrict__ levWout,
                const float* __restrict__ levbout,
                const float* __restrict__ hedWin, const float* __restrict__ hedbin,
                const float* __restrict__ hedbh,  const float* __restrict__ hedbout,
                const ushort* __restrict__ WF, double* __restrict__ accD)
{
    __shared__ ushort bufL[2][64 * 128];   // lev ping-pong (32 KB)
    __shared__ ushort bufH[2][64 * 128];   // hed ping-pong (32 KB)
    __shared__ float  sS[2][64];
    __shared__ float  sHc[64];

    const int tid  = threadIdx.x;
    const int wv   = tid >> 6;
    const int half = wv >> 2;      // 0 = lev chain, 1 = hed chain
    const int wvm  = wv & 3;
    const int l    = tid & 63;
    const int g    = l >> 4;
    const int c15  = l & 15;
    const int bp0  = blockIdx.x * 64;

    if (tid < 64) sS[0][tid] = 1.0f;
    float hedg[4][4];
#pragma unroll
    for (int a = 0; a < 4; ++a)
#pragma unroll
        for (int b = 0; b < 4; ++b) hedg[a][b] = 0.f;
    float dfim1 = 1.0f;
    __syncthreads();

    for (int i = 1; i <= 96; ++i) {
        const int idx = (i - 1) / 12;
        const float t = (float)(i - 1) * DT_F;
        const float* sScur = sS[(i - 1) & 1];
        float* sSnxt = sS[i & 1];
        const ushort* WFi = WF + (size_t)idx * 106496;

        ushort* A = half ? bufH[0] : bufL[0];
        ushort* B = half ? bufH[1] : bufL[1];
        const float* Win  = (half ? hedWin : levWin) + idx * 256;
        const float* binp = (half ? hedbin : levbin) + (idx << 7);
        const float* bh   = (half ? hedbh  : levbh)  + idx * 384;
        const ushort* Wm  = WFi + ((half * 3) << 14);

        // W1: layer1 (both chains) + normals prefetch (lev; hidden by W1-W4)
        layer1(Win, binp, t, sScur, A, wvm, l);
        float nrm = 0.f;
        if (half == 0) nrm = normals[(size_t)(i - 1) * 16384 + bp0 + c15 + (wvm << 4)];
        __syncthreads();                                    // b1
        hidden32(Wm,              bh,       A, B, wvm, l);
        __syncthreads();                                    // b2
        hidden32(Wm + 16384,      bh + 128, B, A, wvm, l);
        __syncthreads();                                    // b3
        hidden32(Wm + 32768,      bh + 256, A, B, wvm, l);
        __syncthreads();                                    // b4

        const float dfi = dfim1 * DF_F;
        f32x4v acc0 = {0,0,0,0}, acc1 = acc0, acc2 = acc0, acc3 = acc0;
        if (half == 0) {
            // lev-out (1x128 dot) + SDE; wave wvm owns cols 16*wvm..+16
            const float* Wo = levWout + (idx << 7);
            float wk[32];
#pragma unroll
            for (int kb = 0; kb < 8; ++kb)
                *(f32x4v*)&wk[4 * kb] = *(const f32x4v*)&Wo[(g << 5) + (kb << 2)];
            const int c = c15 + (wvm << 4);
            float p = 0.f;
#pragma unroll
            for (int kb = 0; kb < 4; ++kb) {
                short8 hv = *(const short8*)&bufL[1][SWZ(c, (g << 5) + (kb << 3))];
#pragma unroll
                for (int j = 0; j < 8; ++j) p = fmaf(bf2f(hv[j]), wk[(kb << 3) + j], p);
            }
            p += __shfl_xor(p, 16);
            p += __shfl_xor(p, 32);
            p += levbout[idx];
            const float lv = (p > 20.f) ? p : __logf(1.f + __expf(p));   // softplus
            const float S = sScur[c];
            const float drift = S * RFR_F / (1.f + fabsf(S * RFR_F) * SQDT_F);
            const float dif   = S * lv    / (1.f + fabsf(S * lv)   * SQDT_F);
            const float dW = SQDT_F * nrm;
            const float Sn = S + drift * DT_F + dif * dW;
            if (g == 0) { sSnxt[c] = Sn; sHc[c] = dfim1 * (S * dif) * dW; }
        } else {
            // hed-out 64x128 via 16x16x32 MFMA; wave wvm owns rows 16*wvm..+16
            const short8* fb = (const short8*)(WFi + 98304 + (wvm << 11));
            __builtin_amdgcn_s_setprio(1);
#pragma unroll
            for (int kcq = 0; kcq < 4; ++kcq) {
                short8 a = fb[kcq * 64 + l];
                const int k0 = (kcq << 5) + (g << 3);
                short8 b0 = *(const short8*)&bufH[1][SWZ(c15,      k0)];
                short8 b1 = *(const short8*)&bufH[1][SWZ(16 + c15, k0)];
                short8 b2 = *(const short8*)&bufH[1][SWZ(32 + c15, k0)];
                short8 b3 = *(const short8*)&bufH[1][SWZ(48 + c15, k0)];
                acc0 = __builtin_amdgcn_mfma_f32_16x16x32_bf16(a, b0, acc0, 0, 0, 0);
                acc1 = __builtin_amdgcn_mfma_f32_16x16x32_bf16(a, b1, acc1, 0, 0, 0);
                acc2 = __builtin_amdgcn_mfma_f32_16x16x32_bf16(a, b2, acc2, 0, 0, 0);
                acc3 = __builtin_amdgcn_mfma_f32_16x16x32_bf16(a, b3, acc3, 0, 0, 0);
            }
            __builtin_amdgcn_s_setprio(0);
        }
        __syncthreads();                                    // b5

        if (half == 1) {
            // hedging accumulation; C/D row j = 16*wvm + 4g + ii, col = 16*ct + c15
            const f32x4v bo4 = *(const f32x4v*)&hedbout[(idx << 6) + (wvm << 4) + (g << 2)];
            const float hc0 = sHc[c15], hc1 = sHc[16 + c15], hc2 = sHc[32 + c15], hc3 = sHc[48 + c15];
#pragma unroll
            for (int ii = 0; ii < 4; ++ii) {
                hedg[0][ii] = fmaf(hc0, acc0[ii] + bo4[ii], hedg[0][ii]);
                hedg[1][ii] = fmaf(hc1, acc1[ii] + bo4[ii], hedg[1][ii]);
                hedg[2][ii] = fmaf(hc2, acc2[ii] + bo4[ii], hedg[2][ii]);
                hedg[3][ii] = fmaf(hc3, acc3[ii] + bo4[ii], hedg[3][ii]);
            }
            if ((i % 12) == 0) {
                const int m = i / 12 - 1;
                const int isel = m & 3;
                const bool active = ((m >> 2) == (g & 1));
                const int ks = (wvm << 1) + (g >> 1);
                float s_ = 0.f, q_ = 0.f;
                if (active) {
                    const float K = strikes[ks];
#pragma unroll
                    for (int ct = 0; ct < 4; ++ct) {
                        const float* hrow = hedg[ct];
                        const float hv = (isel == 0) ? hrow[0] : (isel == 1) ? hrow[1]
                                        : (isel == 2) ? hrow[2] : hrow[3];
                        const float Sn = sSnxt[(ct << 4) + c15];
                        const float sim = dfi * fmaxf(Sn - K, 0.f) - hv;
                        s_ += sim; q_ += sim * sim;
                    }
                }
#pragma unroll
                for (int off = 1; off < 16; off <<= 1) {
                    s_ += __shfl_xor(s_, off);
                    q_ += __shfl_xor(q_, off);
                }
                if (active && c15 == 0) {
                    const int rep = blockIdx.x & 31;
                    atomicAdd(&accD[rep * 128 + ks * 8 + m], (double)s_);
                    atomicAdd(&accD[rep * 128 + 64 + ks * 8 + m], (double)q_);
                }
            }
        }
        dfim1 = dfi;
    }
}

// prep: pack bf16 weights into MFMA fragment order + zero accumulators
// per idx (106496 ushorts): 6x [128x128] hidden (16384 each, 32x32x16 frags) then [64x128] hed-out (8192, 16x16x32 frags)
__global__ void prep_kernel(const float* __restrict__ levWh, const float* __restrict__ hedWh,
                            const float* __restrict__ hedWout,
                            ushort* __restrict__ WF, double* __restrict__ accD)
{
    const long long stride = (long long)gridDim.x * blockDim.x;
    const long long t0 = (long long)blockIdx.x * blockDim.x + threadIdx.x;
    for (long long e = t0; e < 851968LL; e += stride) {
        const int idx = (int)(e / 106496);
        const int rem = (int)(e % 106496);
        float val;
        if (rem < 98304) {                        // 6 hidden matrices
            const int m    = rem >> 14;
            const int r2   = rem & 16383;
            const int slot = r2 >> 9;             // rb*8 + kc
            const int rb   = slot >> 3;
            const int kc   = slot & 7;
            const int lane = (r2 >> 3) & 63;
            const int j    = r2 & 7;
            const int r = (rb << 5) + (lane & 31);
            const int k = (kc << 4) + ((lane >> 5) << 3) + j;
            const float* src = (m < 3) ? levWh : hedWh;
            const int mm = (m < 3) ? m : m - 3;
            val = src[(((idx * 3 + mm) << 7) + r) * 128 + k];
        } else {                                  // hed-out 64x128
            const int r3   = rem - 98304;
            const int slot = r3 >> 9;             // rb*4 + kcq
            const int rb   = slot >> 2;
            const int kcq  = slot & 3;
            const int lane = (r3 >> 3) & 63;
            const int j    = r3 & 7;
            const int r = (rb << 4) + (lane & 15);
            const int k = (kcq << 5) + ((lane >> 4) << 3) + j;
            val = hedWout[(idx << 13) + (r << 7) + k];
        }
        WF[e] = (ushort)f2bf(val);
    }
    for (long long e = t0; e < 4096; e += stride) accD[e] = 0.0;
}

__global__ void finalize_kernel(const double* __restrict__ accD, float* __restrict__ out)
{
    const int t = threadIdx.x;
    if (t < 64) {
        double s = 0.0, q = 0.0;
        for (int rep = 0; rep < 32; ++rep) {
            s += accD[rep * 128 + t];
            q += accD[rep * 128 + 64 + t];
        }
        out[t]      = (float)(s / 16384.0);
        out[64 + t] = (float)((q - s * s / 16384.0) / 16383.0);
    }
}

extern "C" void kernel_launch(void* const* d_in, const int* in_sizes, int n_in,
                              void* d_out, int out_size, void* d_ws, size_t ws_size,
                              hipStream_t stream)
{
    const float* normals = (const float*)d_in[0];
    const float* strikes = (const float*)d_in[1];
    const float* levWin  = (const float*)d_in[2];
    const float* levbin  = (const float*)d_in[3];
    const float* levWh   = (const float*)d_in[4];
    const float* levbh   = (const float*)d_in[5];
    const float* levWout = (const float*)d_in[6];
    const float* levbout = (const float*)d_in[7];
    const float* hedWin  = (const float*)d_in[8];
    const float* hedbin  = (const float*)d_in[9];
    const float* hedWh   = (const float*)d_in[10];
    const float* hedbh   = (const float*)d_in[11];
    const float* hedWout = (const float*)d_in[12];
    const float* hedbout = (const float*)d_in[13];

    ushort* WF   = (ushort*)d_ws;                      // 851,968 ushorts = 1,703,936 B
    double* accD = (double*)((char*)d_ws + 1703936);   // 4096 doubles

    prep_kernel<<<1024, 256, 0, stream>>>(levWh, hedWh, hedWout, WF, accD);
    sim_kernel<<<256, 512, 0, stream>>>(normals, strikes,
                                        levWin, levbin, levbh, levWout, levbout,
                                        hedWin, hedbin, hedbh, hedbout,
                                        WF, accD);
    finalize_kernel<<<1, 64, 0, stream>>>(accD, (float*)d_out);
}